// Round 1
// baseline (663.003 us; speedup 1.0000x reference)
//
#include <hip/hip_runtime.h>

#define V 8
#define E 256
#define LAGS 4
#define WIN 64
#define STEP 16
#define KCB 512
#define BB 32
#define SS 8256
#define TT 512          // (SS - WIN) / STEP
#define CONV_OUT 16
#define WPB 16          // windows per block
#define TPB 256
#define NPOS 76         // 4*(WPB-1) + CONV_OUT conv positions per block
#define NCHUNK 19       // NPOS / 4
#define YSTRIDE 80      // padded row stride (floats), 16B-aligned rows
#define XSPAN 304       // (WPB-1)*STEP + WIN

// LDS float offsets
#define OFF_YS   0          // [128][YSTRIDE] = 10240 floats (per e'-half)
#define OFF_XS   10240      // [V][XSPAN] = 2432 floats (conv phase)
#define OFF_ES   10240      // [WPB][E] = 4096 floats (after xs dead)
#define OFF_SC   0          // [WPB][E] scores  (reuses ys)
#define OFF_SI   4096       // [WPB][E] indices (reuses ys)
#define OFF_PS   8192       // [WPB][16] partial scores
#define OFF_PI   8448       // [WPB][16] partial idx
#define OFF_IW   8704       // [WPB] winners
#define SMEM_FLOATS 14336   // 57344 bytes

__device__ __forceinline__ float f4get(const float4& v, int i) {
  return i == 0 ? v.x : (i == 1 ? v.y : (i == 2 ? v.z : v.w));
}

__device__ __forceinline__ float conv_one(const float* xs, int p, const float4* cw, float cb0) {
  float a = cb0;
#pragma unroll
  for (int v = 0; v < V; ++v) {
    const float4 xv = *(const float4*)(xs + v * XSPAN + 4 * p);
    a = fmaf(xv.x, cw[v].x, a);
    a = fmaf(xv.y, cw[v].y, a);
    a = fmaf(xv.z, cw[v].z, a);
    a = fmaf(xv.w, cw[v].w, a);
  }
  return fmaxf(a, 0.0f);
}

__global__ __launch_bounds__(TPB, 2)
void tok_fused(const float* __restrict__ x, const float* __restrict__ conv_w,
               const float* __restrict__ conv_b, const float* __restrict__ lin_w,
               const float* __restrict__ lin_b, const float* __restrict__ cbk,
               float* __restrict__ out)
{
  __shared__ float smem[SMEM_FLOATS];
  float* ys = smem + OFF_YS;
  float* xs = smem + OFF_XS;
  float* es = smem + OFF_ES;
  float* sc = smem + OFF_SC;
  int*   si = (int*)(smem + OFF_SI);
  float* ps = smem + OFF_PS;
  int*   pi = (int*)(smem + OFF_PI);
  int*   iw = (int*)(smem + OFF_IW);

  const int tid = threadIdx.x;
  const int b   = blockIdx.x >> 5;
  const int t0  = (blockIdx.x & 31) * WPB;

  // ---- Phase 1: stage x window span into LDS ----
  const float* xb = x + (size_t)b * V * SS + (size_t)t0 * STEP;
#pragma unroll
  for (int v = 0; v < V; ++v) {
    for (int j = tid; j < XSPAN; j += TPB)
      xs[v * XSPAN + j] = xb[(size_t)v * SS + j];
  }

  double accd[WPB];
#pragma unroll
  for (int w = 0; w < WPB; ++w) accd[w] = 0.0;

  for (int half = 0; half < 2; ++half) {
    __syncthreads();  // xs ready (h0) / ys free after previous linear (h1)

    // ---- Phase 2: conv for e' in [half*128, half*128+128) ----
    {
      const int ep  = half * 128 + (tid >> 1);
      const int row = ep & 127;
      float4 cw[V];
      const float4* cwp = (const float4*)(conv_w + (size_t)ep * (V * LAGS));
#pragma unroll
      for (int v = 0; v < V; ++v) cw[v] = cwp[v];
      const float cb0 = conv_b[ep];
      const int c0 = (tid & 1) ? 10 : 0;
      const int c1 = (tid & 1) ? NCHUNK : 10;
      for (int c = c0; c < c1; ++c) {
        const int p = 4 * c;
        float r0 = conv_one(xs, p + 0, cw, cb0);
        float r1 = conv_one(xs, p + 1, cw, cb0);
        float r2 = conv_one(xs, p + 2, cw, cb0);
        float r3 = conv_one(xs, p + 3, cw, cb0);
        *(float4*)(ys + row * YSTRIDE + 4 * c) = make_float4(r0, r1, r2, r3);
      }
    }
    __syncthreads();  // ys ready

    // ---- Phase 3: linear, thread = output dim eo = tid ----
    const float* lwbase = lin_w + (size_t)tid * (E * CONV_OUT) + half * (128 * CONV_OUT);
    float4 nA, nB, nC, nD;
    {
      const float4* p4 = (const float4*)(lwbase);
      nA = p4[0]; nB = p4[1]; nC = p4[2]; nD = p4[3];
    }
    for (int er = 0; er < 128; ++er) {
      const float4 lA = nA, lB = nB, lC = nC, lD = nD;
      const int ern = (er + 1) & 127;   // wraps harmlessly on last iter
      {
        const float4* p4 = (const float4*)(lwbase + ern * CONV_OUT);
        nA = p4[0]; nB = p4[1]; nC = p4[2]; nD = p4[3];
      }
      float4 yr[NCHUNK];
      const float4* yp = (const float4*)(ys + er * YSTRIDE);
#pragma unroll
      for (int q = 0; q < NCHUNK; ++q) yr[q] = yp[q];

      float it[WPB];
#pragma unroll
      for (int w = 0; w < WPB; ++w) it[w] = 0.0f;
#pragma unroll
      for (int o = 0; o < CONV_OUT; ++o) {
        const float lw_o = f4get(o < 4 ? lA : (o < 8 ? lB : (o < 12 ? lC : lD)), o & 3);
#pragma unroll
        for (int w = 0; w < WPB; ++w) {
          const int p = 4 * w + o;
          it[w] = fmaf(lw_o, f4get(yr[p >> 2], p & 3), it[w]);
        }
      }
#pragma unroll
      for (int w = 0; w < WPB; ++w) accd[w] += (double)it[w];
    }
  }

  // ---- write e rows to LDS (region B; xs dead) ----
#pragma unroll
  for (int w = 0; w < WPB; ++w)
    es[w * E + tid] = (float)accd[w] + lin_b[tid];
  __syncthreads();

  // ---- Phase 4: distances; thread handles codebook rows tid and tid+256 ----
  float s_best[WPB];
  int   i_best[WPB];
#pragma unroll
  for (int jj = 0; jj < 2; ++jj) {
    const int j = tid + jj * 256;
    const float4* cbp = (const float4*)(cbk + (size_t)j * E);
    double sd[WPB];
#pragma unroll
    for (int w = 0; w < WPB; ++w) sd[w] = 0.0;
    double nd = 0.0;
    for (int i4 = 0; i4 < E / 4; ++i4) {
      const float4 c4 = cbp[i4];
      float nt = c4.x * c4.x;
      nt = fmaf(c4.y, c4.y, nt);
      nt = fmaf(c4.z, c4.z, nt);
      nt = fmaf(c4.w, c4.w, nt);
      nd += (double)nt;
#pragma unroll
      for (int w = 0; w < WPB; ++w) {
        const float4 e4 = *(const float4*)(es + w * E + i4 * 4);
        float t = c4.x * e4.x;
        t = fmaf(c4.y, e4.y, t);
        t = fmaf(c4.z, e4.z, t);
        t = fmaf(c4.w, e4.w, t);
        sd[w] += (double)t;
      }
    }
#pragma unroll
    for (int w = 0; w < WPB; ++w) {
      const float s = (float)(sd[w] - 0.5 * nd);
      if (jj == 0) {
        s_best[w] = s; i_best[w] = j;
      } else if (s > s_best[w]) {   // strict >: ties keep lower j
        s_best[w] = s; i_best[w] = j;
      }
    }
  }
#pragma unroll
  for (int w = 0; w < WPB; ++w) {
    sc[w * E + tid] = s_best[w];
    si[w * E + tid] = i_best[w];
  }
  __syncthreads();

  // ---- Phase 5: argmax reduce with min-index tie-break ----
  {
    const int w = tid >> 4, seg = tid & 15;
    float m = -INFINITY; int mi = 0x7fffffff;
    for (int t = seg * 16; t < seg * 16 + 16; ++t) {
      const float s = sc[w * E + t];
      const int   jx = si[w * E + t];
      if (s > m || (s == m && jx < mi)) { m = s; mi = jx; }
    }
    ps[w * 16 + seg] = m; pi[w * 16 + seg] = mi;
  }
  __syncthreads();
  if (tid < WPB) {
    const int w = tid;
    float m = -INFINITY; int mi = 0x7fffffff;
    for (int t = 0; t < 16; ++t) {
      const float s = ps[w * 16 + t];
      const int   jx = pi[w * 16 + t];
      if (s > m || (s == m && jx < mi)) { m = s; mi = jx; }
    }
    iw[w] = mi;
  }
  __syncthreads();

  // ---- Phase 6: out[b, t0+w, :] = codebook[iw[w], :] ----
  const size_t outb = ((size_t)b * TT + t0) * E;
#pragma unroll
  for (int w = 0; w < WPB; ++w)
    out[outb + (size_t)w * E + tid] = cbk[(size_t)iw[w] * E + tid];
}

extern "C" void kernel_launch(void* const* d_in, const int* in_sizes, int n_in,
                              void* d_out, int out_size, void* d_ws, size_t ws_size,
                              hipStream_t stream) {
  const float* x      = (const float*)d_in[0];
  const float* conv_w = (const float*)d_in[1];
  const float* conv_b = (const float*)d_in[2];
  const float* lin_w  = (const float*)d_in[3];
  const float* lin_b  = (const float*)d_in[4];
  const float* cbk    = (const float*)d_in[5];
  float* out = (float*)d_out;

  tok_fused<<<dim3(BB * (TT / WPB)), dim3(TPB), 0, stream>>>(
      x, conv_w, conv_b, lin_w, lin_b, cbk, out);
}